// Round 1
// baseline (143.173 us; speedup 1.0000x reference)
//
#include <hip/hip_runtime.h>
#include <cstdint>
#include <cstddef>

#define DD        2048
#define NE        8
#define NTOK      4096
#define CAP       512
#define TOKS_PER_BLK 16
#define NBLK1     (NTOK / TOKS_PER_BLK)   // 256
#define DISP_ELEMS (NTOK * NE * CAP)      // 16,777,216 floats
#define GATES_OFF  DISP_ELEMS
#define IDX_OFF    (DISP_ELEMS + NTOK * 2)

// ---------------------------------------------------------------------------
// Kernel 1: zero dispatcher slice + logits (f64 accum) + top-2 + softmax.
// Each block: 256 threads, 16 tokens. Thread t owns d in [t*8, t*8+8), so its
// 8x8 W slice lives in 64 VGPRs (re-read per block from L2, 16 MB total).
// ---------------------------------------------------------------------------
__global__ __launch_bounds__(256) void k_logits(
    const float* __restrict__ x, const float* __restrict__ W,
    float* __restrict__ out, int* __restrict__ choices)
{
    const int tid = threadIdx.x;
    const int bid = blockIdx.x;

    // ---- Phase 0: zero this block's slice of the dispatcher -------------
    // 4,194,304 float4 total / 256 blocks = 16384 / 256 threads = 64 each.
    {
        float4 z = make_float4(0.f, 0.f, 0.f, 0.f);
        float4* dp = reinterpret_cast<float4*>(out);
        size_t base = (size_t)bid * 16384 + tid;
        #pragma unroll
        for (int i = 0; i < 64; ++i)
            dp[base + (size_t)i * 256] = z;
    }

    // ---- Phase 1: W slice into registers --------------------------------
    float wreg[64];
    {
        const float4* W4 = reinterpret_cast<const float4*>(W);
        #pragma unroll
        for (int j = 0; j < 8; ++j) {
            int d = tid * 8 + j;
            float4 a = W4[d * 2];
            float4 b = W4[d * 2 + 1];
            wreg[j * 8 + 0] = a.x; wreg[j * 8 + 1] = a.y;
            wreg[j * 8 + 2] = a.z; wreg[j * 8 + 3] = a.w;
            wreg[j * 8 + 4] = b.x; wreg[j * 8 + 5] = b.y;
            wreg[j * 8 + 6] = b.z; wreg[j * 8 + 7] = b.w;
        }
    }

    __shared__ double redbuf[4][NE];

    const int lane = tid & 63;
    const int wv   = tid >> 6;

    for (int t = 0; t < TOKS_PER_BLK; ++t) {
        const int n = bid * TOKS_PER_BLK + t;
        const float4* xr = reinterpret_cast<const float4*>(x + (size_t)n * DD);
        float4 xa = xr[tid * 2];
        float4 xb = xr[tid * 2 + 1];
        float xv[8] = {xa.x, xa.y, xa.z, xa.w, xb.x, xb.y, xb.z, xb.w};

        double acc[NE];
        #pragma unroll
        for (int e = 0; e < NE; ++e) acc[e] = 0.0;
        #pragma unroll
        for (int j = 0; j < 8; ++j) {
            #pragma unroll
            for (int e = 0; e < NE; ++e)
                acc[e] += (double)xv[j] * (double)wreg[j * 8 + e];
        }

        // wave-64 butterfly reduce for all 8 accumulators
        #pragma unroll
        for (int off = 32; off > 0; off >>= 1) {
            #pragma unroll
            for (int e = 0; e < NE; ++e)
                acc[e] += __shfl_xor(acc[e], off, 64);
        }
        if (lane == 0) {
            #pragma unroll
            for (int e = 0; e < NE; ++e) redbuf[wv][e] = acc[e];
        }
        __syncthreads();

        if (tid == 0) {
            float lg[NE];
            #pragma unroll
            for (int e = 0; e < NE; ++e)
                lg[e] = (float)(redbuf[0][e] + redbuf[1][e] + redbuf[2][e] + redbuf[3][e]);

            // top-2, strict > keeps lowest index on ties (matches jax.lax.top_k)
            int e0 = 0;
            #pragma unroll
            for (int e = 1; e < NE; ++e) if (lg[e] > lg[e0]) e0 = e;
            int e1 = (e0 == 0) ? 1 : 0;
            #pragma unroll
            for (int e = 0; e < NE; ++e)
                if (e != e0 && lg[e] > lg[e1] && !(e > e1 && lg[e] == lg[e1])) {
                    // strict >: first (lowest) index among maxima of the rest
                    if (lg[e] > lg[e1]) e1 = e;
                }
            // (re-do cleanly: lowest-index argmax over e != e0)
            {
                int best = -1;
                #pragma unroll
                for (int e = 0; e < NE; ++e) {
                    if (e == e0) continue;
                    if (best < 0 || lg[e] > lg[best]) best = e;
                }
                e1 = best;
            }

            float l0 = lg[e0], l1 = lg[e1];
            float p1 = __expf(l1 - l0);      // l0 >= l1, stable
            float s  = 1.0f + p1;
            float g0 = 1.0f / s;
            float g1 = p1 / s;

            float* gates = out + GATES_OFF;
            float* idxo  = out + IDX_OFF;
            gates[n * 2 + 0] = g0;
            gates[n * 2 + 1] = g1;
            idxo[n * 2 + 0]  = (float)e0;
            idxo[n * 2 + 1]  = (float)e1;
            choices[n * 2 + 0] = e0;
            choices[n * 2 + 1] = e1;
        }
        __syncthreads();
    }
}

// ---------------------------------------------------------------------------
// Kernel 2: single-block sequential-ordered scan over 4096 tokens.
// 16 independent (k-slot, expert) running counts; ballot gives in-wave rank,
// 16 scan threads carry wave bases across the 4 sweeps. Valid tokens scatter
// 1.0f into dispatcher[n, e, priority].
// ---------------------------------------------------------------------------
__global__ __launch_bounds__(1024) void k_scan(
    const int* __restrict__ choices, float* __restrict__ out)
{
    __shared__ unsigned waveTot[16][16];   // [wave][pair]
    __shared__ unsigned waveBase[16][16];
    __shared__ unsigned baseRun[16];

    const int tid  = threadIdx.x;
    const int lane = tid & 63;
    const int wv   = tid >> 6;             // 0..15

    if (tid < 16) baseRun[tid] = 0;
    __syncthreads();

    const unsigned long long below = (lane == 0) ? 0ull : ((~0ull) >> (64 - lane));

    for (int sweep = 0; sweep < 4; ++sweep) {
        const int n  = sweep * 1024 + tid;
        const int e0 = choices[n * 2 + 0];
        const int e1 = choices[n * 2 + 1];

        unsigned r0 = 0, r1 = 0;
        #pragma unroll
        for (int e = 0; e < NE; ++e) {
            unsigned long long m0 = __ballot(e0 == e);
            unsigned long long m1 = __ballot(e1 == e);
            if (e0 == e) r0 = (unsigned)__popcll(m0 & below);
            if (e1 == e) r1 = (unsigned)__popcll(m1 & below);
            if (lane == 0) {
                waveTot[wv][e]     = (unsigned)__popcll(m0);
                waveTot[wv][8 + e] = (unsigned)__popcll(m1);
            }
        }
        __syncthreads();

        if (tid < 16) {
            unsigned run = baseRun[tid];
            for (int w = 0; w < 16; ++w) {
                waveBase[w][tid] = run;
                run += waveTot[w][tid];
            }
            baseRun[tid] = run;
        }
        __syncthreads();

        unsigned p0 = waveBase[wv][e0]     + r0;   // zero-based priority
        unsigned p1 = waveBase[wv][8 + e1] + r1;
        if (p0 < CAP) out[((size_t)n * NE + e0) * CAP + p0] = 1.0f;
        if (p1 < CAP) out[((size_t)n * NE + e1) * CAP + p1] = 1.0f;
        __syncthreads();   // waveTot reused next sweep
    }
}

extern "C" void kernel_launch(void* const* d_in, const int* in_sizes, int n_in,
                              void* d_out, int out_size, void* d_ws, size_t ws_size,
                              hipStream_t stream) {
    const float* x = (const float*)d_in[0];
    const float* W = (const float*)d_in[1];
    float* out     = (float*)d_out;
    int* choices   = (int*)d_ws;

    hipLaunchKernelGGL(k_logits, dim3(NBLK1), dim3(256), 0, stream, x, W, out, choices);
    hipLaunchKernelGGL(k_scan,   dim3(1),     dim3(1024), 0, stream, choices, out);
}

// Round 2
// 112.559 us; speedup vs baseline: 1.2720x; 1.2720x over previous
//
#include <hip/hip_runtime.h>
#include <cstdint>
#include <cstddef>

#define DD    2048
#define NE    8
#define NTOK  4096
#define CAP   512
#define TPB   4                       // tokens per k_logits block
#define NBLK  (NTOK / TPB)            // 1024
#define DISP_ELEMS (NTOK * NE * CAP)  // 16,777,216 floats
#define GATES_OFF  DISP_ELEMS
#define IDX_OFF    (DISP_ELEMS + NTOK * 2)

// LDS float4-index XOR swizzle: breaks the seg-stride-256B 8-way bank conflict.
__device__ __forceinline__ int swz(int f4idx) { return f4idx ^ ((f4idx >> 4) & 7); }

// ---------------------------------------------------------------------------
// Kernel 1: per 4-token block — zero dispatcher slice, logits (f64 accum),
// top-2 + softmax, choices + per-block (k,expert) histogram.
// Thread t: expert e = t&7, dim segment seg = t>>3 (64 dims), W col in VGPRs.
// ---------------------------------------------------------------------------
__global__ __launch_bounds__(256, 4) void k_logits(
    const float* __restrict__ x, const float* __restrict__ W,
    float* __restrict__ out, int2* __restrict__ choices,
    unsigned* __restrict__ hist)
{
    const int tid  = threadIdx.x;
    const int bid  = blockIdx.x;
    const int e    = tid & 7;
    const int seg  = tid >> 3;        // 0..31
    const int lane = tid & 63;
    const int wv   = tid >> 6;        // 0..3
    const int seg8 = lane >> 3;       // 0..7 within wave

    __shared__ float  xs[TPB * DD];           // 32 KB, accessed swizzled
    __shared__ double redbuf[TPB][4][NE];     // 1 KB
    __shared__ int2   chs[TPB];

    // ---- zero this block's 64 KB dispatcher slice -----------------------
    {
        float4 z = make_float4(0.f, 0.f, 0.f, 0.f);
        float4* dp = reinterpret_cast<float4*>(out) + (size_t)bid * (TPB * NE * CAP / 4);
        #pragma unroll
        for (int i = 0; i < (TPB * NE * CAP / 4) / 256; ++i)   // 16
            dp[i * 256 + tid] = z;
    }

    // ---- W column e, dims [seg*64, seg*64+64) into registers ------------
    float wreg[64];
    const int dbase = seg * 64;
    #pragma unroll
    for (int j = 0; j < 64; ++j)
        wreg[j] = W[(size_t)(dbase + j) * NE + e];

    // ---- stage 4 token rows into LDS (swizzled) -------------------------
    {
        const float4* x4 = reinterpret_cast<const float4*>(x) + (size_t)bid * TPB * (DD / 4);
        float4* s4 = reinterpret_cast<float4*>(xs);
        #pragma unroll
        for (int i = 0; i < TPB * (DD / 4) / 256; ++i)         // 8
            s4[swz(i * 256 + tid)] = x4[i * 256 + tid];
    }
    __syncthreads();

    // ---- f64 dot: acc[t] = sum_j xs[t][dbase+j] * wreg[j] ---------------
    double acc[TPB] = {0.0, 0.0, 0.0, 0.0};
    const float4* s4 = reinterpret_cast<const float4*>(xs);
    #pragma unroll
    for (int jj = 0; jj < 16; ++jj) {
        #pragma unroll
        for (int t = 0; t < TPB; ++t) {
            float4 v = s4[swz(t * (DD / 4) + seg * 16 + jj)];
            acc[t] += (double)v.x * (double)wreg[jj * 4 + 0];
            acc[t] += (double)v.y * (double)wreg[jj * 4 + 1];
            acc[t] += (double)v.z * (double)wreg[jj * 4 + 2];
            acc[t] += (double)v.w * (double)wreg[jj * 4 + 3];
        }
    }

    // ---- reduce across the 8 same-expert lanes in this wave -------------
    #pragma unroll
    for (int off = 8; off <= 32; off <<= 1) {
        #pragma unroll
        for (int t = 0; t < TPB; ++t)
            acc[t] += __shfl_xor(acc[t], off, 64);
    }
    if (seg8 == 0) {
        #pragma unroll
        for (int t = 0; t < TPB; ++t)
            redbuf[t][wv][e] = acc[t];
    }
    __syncthreads();

    // ---- per-token finalize: threads 0..3 -------------------------------
    if (tid < TPB) {
        const int t = tid;
        const int n = bid * TPB + t;
        float lg[NE];
        #pragma unroll
        for (int q = 0; q < NE; ++q)
            lg[q] = (float)(redbuf[t][0][q] + redbuf[t][1][q] +
                            redbuf[t][2][q] + redbuf[t][3][q]);

        int e0 = 0;
        #pragma unroll
        for (int q = 1; q < NE; ++q) if (lg[q] > lg[e0]) e0 = q;
        int e1 = -1;
        #pragma unroll
        for (int q = 0; q < NE; ++q) {
            if (q == e0) continue;
            if (e1 < 0 || lg[q] > lg[e1]) e1 = q;
        }

        float p1 = __expf(lg[e1] - lg[e0]);    // lg[e0] >= lg[e1]
        float s  = 1.0f + p1;
        out[GATES_OFF + n * 2 + 0] = 1.0f / s;
        out[GATES_OFF + n * 2 + 1] = p1 / s;
        out[IDX_OFF   + n * 2 + 0] = (float)e0;
        out[IDX_OFF   + n * 2 + 1] = (float)e1;
        int2 c; c.x = e0; c.y = e1;
        choices[n] = c;
        chs[t] = c;
    }
    __syncthreads();

    // ---- per-block histogram: pair p = k*8+e, layout [pair][block] ------
    if (tid < 16) {
        const int k = tid >> 3, ee = tid & 7;
        unsigned c = 0;
        #pragma unroll
        for (int t = 0; t < TPB; ++t) {
            int v = k ? chs[t].y : chs[t].x;
            c += (v == ee);
        }
        hist[tid * NBLK + bid] = c;
    }
}

// ---------------------------------------------------------------------------
// Kernel 2: one block, 1024 threads (16 waves).
// Phase A: wave p does an exclusive scan of hist[p][0..1023] -> bases (LDS).
// Phase B: thread ab owns 4-token A-block ab: rank-in-block + scatter 1.0f.
// ---------------------------------------------------------------------------
__global__ __launch_bounds__(1024) void k_finish(
    const int2* __restrict__ choices, const unsigned* __restrict__ hist,
    float* __restrict__ out)
{
    __shared__ unsigned bases[16][NBLK];   // 64 KB

    const int tid  = threadIdx.x;
    const int lane = tid & 63;
    const int p    = tid >> 6;             // pair 0..15

    // ---- per-pair exclusive scan over 1024 block counts -----------------
    {
        unsigned v[16];
        const unsigned* h = hist + p * NBLK + lane * 16;
        #pragma unroll
        for (int j = 0; j < 16; ++j) v[j] = h[j];

        unsigned run = 0;
        #pragma unroll
        for (int j = 0; j < 16; ++j) { unsigned tv = v[j]; v[j] = run; run += tv; }

        unsigned incl = run;
        #pragma unroll
        for (int off = 1; off < 64; off <<= 1) {
            unsigned u = __shfl_up(incl, off, 64);
            if (lane >= off) incl += u;
        }
        const unsigned excl = incl - run;

        unsigned* bp = &bases[p][lane * 16];
        #pragma unroll
        for (int j = 0; j < 16; ++j) bp[j] = excl + v[j];
    }
    __syncthreads();

    // ---- scatter: thread = A-block of 4 tokens --------------------------
    {
        const int ab = tid;                // 0..1023
        int2 c[4];
        #pragma unroll
        for (int t = 0; t < 4; ++t) c[t] = choices[ab * 4 + t];

        #pragma unroll
        for (int t = 0; t < 4; ++t) {
            const int n = ab * 4 + t;
            const int e0 = c[t].x;
            unsigned r0 = 0;
            #pragma unroll
            for (int m = 0; m < 4; ++m) if (m < t) r0 += (c[m].x == e0);
            const unsigned p0 = bases[e0][ab] + r0;
            if (p0 < CAP) out[((size_t)n * NE + e0) * CAP + p0] = 1.0f;

            const int e1 = c[t].y;
            unsigned r1 = 0;
            #pragma unroll
            for (int m = 0; m < 4; ++m) if (m < t) r1 += (c[m].y == e1);
            const unsigned p1 = bases[8 + e1][ab] + r1;
            if (p1 < CAP) out[((size_t)n * NE + e1) * CAP + p1] = 1.0f;
        }
    }
}

extern "C" void kernel_launch(void* const* d_in, const int* in_sizes, int n_in,
                              void* d_out, int out_size, void* d_ws, size_t ws_size,
                              hipStream_t stream) {
    const float* x = (const float*)d_in[0];
    const float* W = (const float*)d_in[1];
    float* out     = (float*)d_out;
    int2* choices  = (int2*)d_ws;                                   // 32 KB
    unsigned* hist = (unsigned*)((char*)d_ws + NTOK * sizeof(int2)); // 64 KB

    hipLaunchKernelGGL(k_logits, dim3(NBLK), dim3(256), 0, stream,
                       x, W, out, choices, hist);
    hipLaunchKernelGGL(k_finish, dim3(1), dim3(1024), 0, stream,
                       choices, hist, out);
}

// Round 7
// 106.305 us; speedup vs baseline: 1.3468x; 1.0588x over previous
//
#include <hip/hip_runtime.h>
#include <cstdint>
#include <cstddef>

#define DD    2048
#define NE    8
#define NTOK  4096
#define CAP   512
#define TPB   4                       // tokens per block (both kernels)
#define NBLK  (NTOK / TPB)            // 1024
#define DISP_ELEMS (NTOK * NE * CAP)  // 16,777,216 floats
#define GATES_OFF  DISP_ELEMS
#define IDX_OFF    (DISP_ELEMS + NTOK * 2)
#define SLICE      (TPB * NE * CAP)   // 16384 floats = 64 KB per block

// LDS float4-index XOR swizzle: breaks the seg-stride-256B 8-way bank conflict.
__device__ __forceinline__ int swz(int f4idx) { return f4idx ^ ((f4idx >> 4) & 7); }

// ---------------------------------------------------------------------------
// Kernel 1: per 4-token block — logits (f64 accum), top-2 + softmax,
// choices + per-block (k,expert) histogram. NO dispatcher writes.
// Thread t: expert e = t&7, dim segment seg = t>>3 (64 dims), W col in VGPRs.
// ---------------------------------------------------------------------------
__global__ __launch_bounds__(256, 4) void k_logits(
    const float* __restrict__ x, const float* __restrict__ W,
    float* __restrict__ out, int2* __restrict__ choices,
    unsigned* __restrict__ hist)
{
    const int tid  = threadIdx.x;
    const int bid  = blockIdx.x;
    const int e    = tid & 7;
    const int seg  = tid >> 3;        // 0..31
    const int lane = tid & 63;
    const int wv   = tid >> 6;        // 0..3
    const int seg8 = lane >> 3;       // 0..7 within wave

    __shared__ float  xs[TPB * DD];           // 32 KB, accessed swizzled
    __shared__ double redbuf[TPB][4][NE];     // 1 KB
    __shared__ int2   chs[TPB];

    // ---- W column e, dims [seg*64, seg*64+64) into registers ------------
    float wreg[64];
    const int dbase = seg * 64;
    #pragma unroll
    for (int j = 0; j < 64; ++j)
        wreg[j] = W[(size_t)(dbase + j) * NE + e];

    // ---- stage 4 token rows into LDS (swizzled) -------------------------
    {
        const float4* x4 = reinterpret_cast<const float4*>(x) + (size_t)bid * TPB * (DD / 4);
        float4* s4 = reinterpret_cast<float4*>(xs);
        #pragma unroll
        for (int i = 0; i < TPB * (DD / 4) / 256; ++i)         // 8
            s4[swz(i * 256 + tid)] = x4[i * 256 + tid];
    }
    __syncthreads();

    // ---- f64 dot: acc[t] = sum_j xs[t][dbase+j] * wreg[j] ---------------
    double acc[TPB] = {0.0, 0.0, 0.0, 0.0};
    const float4* s4 = reinterpret_cast<const float4*>(xs);
    #pragma unroll
    for (int jj = 0; jj < 16; ++jj) {
        #pragma unroll
        for (int t = 0; t < TPB; ++t) {
            float4 v = s4[swz(t * (DD / 4) + seg * 16 + jj)];
            acc[t] += (double)v.x * (double)wreg[jj * 4 + 0];
            acc[t] += (double)v.y * (double)wreg[jj * 4 + 1];
            acc[t] += (double)v.z * (double)wreg[jj * 4 + 2];
            acc[t] += (double)v.w * (double)wreg[jj * 4 + 3];
        }
    }

    // ---- reduce across the 8 same-expert lanes in this wave -------------
    #pragma unroll
    for (int off = 8; off <= 32; off <<= 1) {
        #pragma unroll
        for (int t = 0; t < TPB; ++t)
            acc[t] += __shfl_xor(acc[t], off, 64);
    }
    if (seg8 == 0) {
        #pragma unroll
        for (int t = 0; t < TPB; ++t)
            redbuf[t][wv][e] = acc[t];
    }
    __syncthreads();

    // ---- per-token finalize: threads 0..3 -------------------------------
    if (tid < TPB) {
        const int t = tid;
        const int n = bid * TPB + t;
        float lg[NE];
        #pragma unroll
        for (int q = 0; q < NE; ++q)
            lg[q] = (float)(redbuf[t][0][q] + redbuf[t][1][q] +
                            redbuf[t][2][q] + redbuf[t][3][q]);

        int e0 = 0;
        #pragma unroll
        for (int q = 1; q < NE; ++q) if (lg[q] > lg[e0]) e0 = q;
        int e1 = -1;
        #pragma unroll
        for (int q = 0; q < NE; ++q) {
            if (q == e0) continue;
            if (e1 < 0 || lg[q] > lg[e1]) e1 = q;
        }

        float p1 = __expf(lg[e1] - lg[e0]);    // lg[e0] >= lg[e1]
        float s  = 1.0f + p1;
        out[GATES_OFF + n * 2 + 0] = 1.0f / s;
        out[GATES_OFF + n * 2 + 1] = p1 / s;
        out[IDX_OFF   + n * 2 + 0] = (float)e0;
        out[IDX_OFF   + n * 2 + 1] = (float)e1;
        int2 c; c.x = e0; c.y = e1;
        choices[n] = c;
        chs[t] = c;
    }
    __syncthreads();

    // ---- per-block histogram, layout [block][pair] (64B/block) ----------
    if (tid < 16) {
        const int k = tid >> 3, ee = tid & 7;
        unsigned c = 0;
        #pragma unroll
        for (int t = 0; t < TPB; ++t) {
            int v = k ? chs[t].y : chs[t].x;
            c += (v == ee);
        }
        hist[bid * 16 + tid] = c;
    }
}

// ---------------------------------------------------------------------------
// Kernel 2: 1024 blocks x 256. Block bid:
//   A) base[p] = sum_{b<bid} hist[b][p]  (redundant per-block prefix; hist is
//      64 KB, L2-resident. Thread t only ever touches pair t&15 since
//      256 % 16 == 0, so no cross-pair reduction hazards.)
//   B) compute its 4 tokens' <=8 dispatch targets from choices + base.
//   C) zero its 64 KB dispatcher slice, barrier, patch 1.0f at targets.
// ---------------------------------------------------------------------------
__global__ __launch_bounds__(256) void k_finish(
    const int2* __restrict__ choices, const unsigned* __restrict__ hist,
    float* __restrict__ out)
{
    __shared__ unsigned partial[256];
    __shared__ unsigned base[16];
    __shared__ int tg[TPB * 2];

    const int tid = threadIdx.x;
    const int bid = blockIdx.x;

    // ---- A: per-pair prefix over preceding blocks -----------------------
    {
        unsigned s = 0;
        const int lim = bid * 16;
        for (int i = tid; i < lim; i += 256) s += hist[i];   // i&15 == tid&15
        partial[tid] = s;
    }
    __syncthreads();
    if (tid < 16) {
        unsigned s = 0;
        #pragma unroll
        for (int j = 0; j < 16; ++j) s += partial[tid + 16 * j];
        base[tid] = s;
    }
    __syncthreads();

    // ---- B: targets for this block's 4 tokens ---------------------------
    if (tid == 0) {
        int2 c[TPB];
        #pragma unroll
        for (int t = 0; t < TPB; ++t) c[t] = choices[bid * TPB + t];
        #pragma unroll
        for (int t = 0; t < TPB; ++t) {
            const int e0 = c[t].x;
            unsigned r = 0;
            #pragma unroll
            for (int m = 0; m < TPB; ++m) if (m < t) r += (c[m].x == e0);
            unsigned p0 = base[e0] + r;
            tg[t * 2 + 0] = (p0 < CAP) ? ((t * NE + e0) * CAP + (int)p0) : -1;

            const int e1 = c[t].y;
            r = 0;
            #pragma unroll
            for (int m = 0; m < TPB; ++m) if (m < t) r += (c[m].y == e1);
            unsigned p1 = base[8 + e1] + r;
            tg[t * 2 + 1] = (p1 < CAP) ? ((t * NE + e1) * CAP + (int)p1) : -1;
        }
    }

    // ---- C: zero slice, then patch --------------------------------------
    {
        float4 z = make_float4(0.f, 0.f, 0.f, 0.f);
        float4* dp = reinterpret_cast<float4*>(out) + (size_t)bid * (SLICE / 4);
        #pragma unroll
        for (int i = 0; i < (SLICE / 4) / 256; ++i)            // 16
            dp[i * 256 + tid] = z;
    }
    __syncthreads();
    if (tid < TPB * 2) {
        const int g = tg[tid];
        if (g >= 0) out[(size_t)bid * SLICE + g] = 1.0f;
    }
}

extern "C" void kernel_launch(void* const* d_in, const int* in_sizes, int n_in,
                              void* d_out, int out_size, void* d_ws, size_t ws_size,
                              hipStream_t stream) {
    const float* x = (const float*)d_in[0];
    const float* W = (const float*)d_in[1];
    float* out     = (float*)d_out;
    int2* choices  = (int2*)d_ws;                                    // 32 KB
    unsigned* hist = (unsigned*)((char*)d_ws + NTOK * sizeof(int2)); // 64 KB

    hipLaunchKernelGGL(k_logits, dim3(NBLK), dim3(256), 0, stream,
                       x, W, out, choices, hist);
    hipLaunchKernelGGL(k_finish, dim3(NBLK), dim3(256), 0, stream,
                       choices, hist, out);
}